// Round 19
// baseline (68.050 us; speedup 1.0000x reference)
//
#include <hip/hip_runtime.h>

#define BS  16
#define NN  256
#define HID 128

// 512 blocks: XCD x gets swz in [64x, 64x+64) = batches 2x, 2x+1.
__device__ __forceinline__ int xcd_swz(int bid) {
    return (bid & 7) * 64 + (bid >> 3);
}

// ---------------------------------------------------------------------------
// K1: exact R18. 512 blocks, 512 threads, 8 rows/block. Split-K quarters;
// phase 2 fused ai+aj. Writes h, aiT, ajT.
// ---------------------------------------------------------------------------
__global__ __launch_bounds__(512, 4) void gat_k1(
    const float* __restrict__ x, const float* __restrict__ W_fc,
    const float* __restrict__ b_fc, const float* __restrict__ W_a1,
    const float* __restrict__ b_a1,
    float* __restrict__ aiT, float* __restrict__ ajT, float* __restrict__ h)
{
    __shared__ __align__(16) float xs[8][HID];            // 4KB
    __shared__ __align__(16) float hs[8][HID];            // 4KB
    __shared__ __align__(16) float red[4][2][8][HID];     // 32KB

    const int tid = threadIdx.x;
    const int k   = tid & 127;
    const int q   = tid >> 7;                 // 0..3
    const int swz = xcd_swz(blockIdx.x);
    const int r0  = swz * 8;                  // flat row = b*NN + n0
    const int b   = r0 >> 8;
    const int n0  = r0 & 255;

    for (int t = tid; t < 8 * HID; t += 512)
        xs[t >> 7][t & 127] = x[r0 * HID + t];
    __syncthreads();

    // ---- phase 1: h partials, split-K quarter d in [32q, 32q+32) ----
    {
        float acc[8] = {0,0,0,0,0,0,0,0};
        const int dq = 32 * q;
        #pragma unroll 2
        for (int d = 0; d < 32; d += 4) {
            float w[4];
            #pragma unroll
            for (int t = 0; t < 4; ++t) w[t] = W_fc[(dq + d + t) * HID + k];
            #pragma unroll
            for (int r = 0; r < 8; ++r) {
                const float4 xv = *(const float4*)&xs[r][dq + d];
                acc[r] += xv.x * w[0] + xv.y * w[1] + xv.z * w[2] + xv.w * w[3];
            }
        }
        #pragma unroll
        for (int r = 0; r < 8; ++r) red[q][0][r][k] = acc[r];
    }
    __syncthreads();

    // ---- reduce h: thread (k,q) -> rows 2q, 2q+1; write LDS + global ----
    {
        const float bf = b_fc[k];
        #pragma unroll
        for (int r2 = 0; r2 < 2; ++r2) {
            const int r = 2 * q + r2;
            const float hv = (red[0][0][r][k] + red[1][0][r][k])
                           + (red[2][0][r][k] + red[3][0][r][k]) + bf;
            hs[r][k] = hv;
            h[(r0 + r) * HID + k] = hv;
        }
    }
    __syncthreads();

    // ---- phase 2 FUSED: ai+aj partials over d-quarter, one hs stream ----
    {
        float ai_a[8] = {0,0,0,0,0,0,0,0};
        float aj_a[8] = {0,0,0,0,0,0,0,0};
        const int dq = 32 * q;
        #pragma unroll 2
        for (int d = 0; d < 32; d += 4) {
            float wi[4], wj[4];
            #pragma unroll
            for (int t = 0; t < 4; ++t) {
                wi[t] = W_a1[(dq + d + t) * HID + k];
                wj[t] = W_a1[(HID + dq + d + t) * HID + k];
            }
            #pragma unroll
            for (int r = 0; r < 8; ++r) {
                const float4 hv = *(const float4*)&hs[r][dq + d];
                ai_a[r] += hv.x * wi[0] + hv.y * wi[1] + hv.z * wi[2] + hv.w * wi[3];
                aj_a[r] += hv.x * wj[0] + hv.y * wj[1] + hv.z * wj[2] + hv.w * wj[3];
            }
        }
        #pragma unroll
        for (int r = 0; r < 8; ++r) {
            red[q][0][r][k] = ai_a[r];
            red[q][1][r][k] = aj_a[r];
        }
    }
    __syncthreads();

    // ---- reduce + transposed store: q selects (proj, row-quad) ----
    {
        const int is_aj = q >> 1;
        const int rb4   = (q & 1) * 4;
        const float bias = is_aj ? 0.f : b_a1[k];
        float4 v;
        v.x = (red[0][is_aj][rb4 + 0][k] + red[1][is_aj][rb4 + 0][k])
            + (red[2][is_aj][rb4 + 0][k] + red[3][is_aj][rb4 + 0][k]) + bias;
        v.y = (red[0][is_aj][rb4 + 1][k] + red[1][is_aj][rb4 + 1][k])
            + (red[2][is_aj][rb4 + 1][k] + red[3][is_aj][rb4 + 1][k]) + bias;
        v.z = (red[0][is_aj][rb4 + 2][k] + red[1][is_aj][rb4 + 2][k])
            + (red[2][is_aj][rb4 + 2][k] + red[3][is_aj][rb4 + 2][k]) + bias;
        v.w = (red[0][is_aj][rb4 + 3][k] + red[1][is_aj][rb4 + 3][k])
            + (red[2][is_aj][rb4 + 3][k] + red[3][is_aj][rb4 + 3][k]) + bias;
        float* dst = (is_aj ? ajT : aiT) + (b * HID + k) * NN + n0 + rb4;
        *(float4*)dst = v;
    }
}

// ---------------------------------------------------------------------------
// K2: WAVE-AUTONOMOUS. 512 blocks, 512 threads, 8-row tile; wave w owns row
// i0+w end-to-end. Wave-private LDS slices (aiw, pscr) — same-wave
// ds_write/ds_read needs no barrier. Phases A/softmax/B barrier-free; ONE
// __syncthreads before the small phase C (out = hp@W_out).
// ---------------------------------------------------------------------------
__global__ __launch_bounds__(512, 4) void gat_k2(
    const float* __restrict__ aiT, const float* __restrict__ ajT,
    const float* __restrict__ h,  const int* __restrict__ adj,
    const float* __restrict__ w_a2, const float* __restrict__ b_a2,
    const float* __restrict__ W_out, const float* __restrict__ b_out,
    float* __restrict__ out)
{
    __shared__ __align__(16) float2 aiw[8][HID];   // per-wave {ai_r, wk}, 8KB
    __shared__ __align__(16) float  pscr[8][NN];   // per-wave p, 8KB
    __shared__ __align__(16) float  hp[8][HID];    // 4KB

    const int tid = threadIdx.x;
    const int swz = xcd_swz(blockIdx.x);
    const int b   = swz >> 5;
    const int i0  = (swz & 31) * 8;
    const int w   = tid >> 6, lane = tid & 63;
    const int r   = i0 + w;                  // this wave's i-row

    // wave-private staging: {ai_r[kk], w2[kk]}; lane covers kk = lane, lane+64
    #pragma unroll
    for (int t = 0; t < 2; ++t) {
        const int kk = t * 64 + lane;
        float2 v;
        v.x = aiT[(b * HID + kk) * NN + r];
        v.y = w_a2[kk];
        aiw[w][kk] = v;
    }
    // adj prefetch for this row (lane owns j = 4*lane .. 4*lane+3)
    const int4 am = *(const int4*)(adj + (b * NN + r) * NN + 4 * lane);
    // NO barrier: only wave w reads aiw[w] (same-wave LDS is in-order)

    // ---- phase A: e[r][j], full k-range per wave ----
    float4 acc = {0.f, 0.f, 0.f, 0.f};
    {
        const float* ajp = ajT + b * HID * NN + 4 * lane;
        #pragma unroll 8
        for (int kk = 0; kk < HID; ++kk) {
            const float4 a4 = *(const float4*)(ajp + kk * NN);
            const float2 aw = aiw[w][kk];
            acc.x = __builtin_fmaf(fmaxf(aw.x + a4.x, 0.f), aw.y, acc.x);
            acc.y = __builtin_fmaf(fmaxf(aw.x + a4.y, 0.f), aw.y, acc.y);
            acc.z = __builtin_fmaf(fmaxf(aw.x + a4.z, 0.f), aw.y, acc.z);
            acc.w = __builtin_fmaf(fmaxf(aw.x + a4.w, 0.f), aw.y, acc.w);
        }
    }

    // ---- mask + softmax (wave-local, no barrier) ----
    {
        const float ba2 = b_a2[0];
        const float e0 = am.x ? acc.x + ba2 : -1e9f;
        const float e1 = am.y ? acc.y + ba2 : -1e9f;
        const float e2 = am.z ? acc.z + ba2 : -1e9f;
        const float e3 = am.w ? acc.w + ba2 : -1e9f;
        float m = fmaxf(fmaxf(e0, e1), fmaxf(e2, e3));
        #pragma unroll
        for (int off = 32; off; off >>= 1) m = fmaxf(m, __shfl_xor(m, off));
        const float p0 = __expf(e0 - m), p1 = __expf(e1 - m);
        const float p2 = __expf(e2 - m), p3 = __expf(e3 - m);
        float s = (p0 + p1) + (p2 + p3);
        #pragma unroll
        for (int off = 32; off; off >>= 1) s += __shfl_xor(s, off);
        const float inv = 1.f / s;
        const float4 pv = {p0 * inv, p1 * inv, p2 * inv, p3 * inv};
        *(float4*)&pscr[w][4 * lane] = pv;   // wave-private
    }
    // NO barrier

    // ---- phase B: hp[r] = P[r] @ h; lane owns k-pair 2*lane, 2*lane+1 ----
    {
        float2 o = {0.f, 0.f};
        const float* hb = h + b * NN * HID + 2 * lane;
        #pragma unroll 4
        for (int j = 0; j < NN; ++j) {
            const float2 hv = *(const float2*)(hb + j * HID);
            const float pj = pscr[w][j];     // uniform read, own slice
            o.x = __builtin_fmaf(pj, hv.x, o.x);
            o.y = __builtin_fmaf(pj, hv.y, o.y);
        }
        *(float2*)&hp[w][2 * lane] = o;
    }
    __syncthreads();   // THE ONLY BARRIER

    // ---- phase C: out = hp @ W_out + b_out; thread (k,q) -> rows 2q,2q+1 ----
    {
        const int k = tid & 127, q = tid >> 7;
        const float bo = b_out[k];
        float o0 = bo, o1 = bo;
        #pragma unroll 2
        for (int d0 = 0; d0 < HID; d0 += 4) {
            float wv[4];
            #pragma unroll
            for (int t = 0; t < 4; ++t) wv[t] = W_out[(d0 + t) * HID + k];
            const float4 hA = *(const float4*)&hp[2 * q + 0][d0];
            const float4 hB = *(const float4*)&hp[2 * q + 1][d0];
            o0 += hA.x * wv[0] + hA.y * wv[1] + hA.z * wv[2] + hA.w * wv[3];
            o1 += hB.x * wv[0] + hB.y * wv[1] + hB.z * wv[2] + hB.w * wv[3];
        }
        out[(b * NN + i0 + 2 * q + 0) * HID + k] = o0;
        out[(b * NN + i0 + 2 * q + 1) * HID + k] = o1;
    }
}

extern "C" void kernel_launch(void* const* d_in, const int* in_sizes, int n_in,
                              void* d_out, int out_size, void* d_ws, size_t ws_size,
                              hipStream_t stream) {
    const float* x     = (const float*)d_in[0];
    const int*   adj   = (const int*)  d_in[1];
    const float* W_fc  = (const float*)d_in[2];
    const float* b_fc  = (const float*)d_in[3];
    const float* W_a1  = (const float*)d_in[4];
    const float* b_a1  = (const float*)d_in[5];
    const float* w_a2  = (const float*)d_in[6];
    const float* b_a2  = (const float*)d_in[7];
    const float* W_out = (const float*)d_in[8];
    const float* b_out = (const float*)d_in[9];
    float* out = (float*)d_out;

    float* ws  = (float*)d_ws;
    float* aiT = ws;                      // aiT[b][k][n]
    float* ajT = ws + BS * NN * HID;      // ajT[b][k][n]
    float* hbuf= ws + 2 * BS * NN * HID;  // h[b][n][k]

    gat_k1<<<BS * NN / 8, 512, 0, stream>>>(x, W_fc, b_fc, W_a1, b_a1,
                                            aiT, ajT, hbuf);
    gat_k2<<<BS * (NN / 8), 512, 0, stream>>>(aiT, ajT, hbuf, adj, w_a2, b_a2,
                                              W_out, b_out, out);
}

// Round 20
// 36.005 us; speedup vs baseline: 1.8900x; 1.8900x over previous
//
#include <hip/hip_runtime.h>

#define BS  16
#define NN  256
#define HID 128

// 512 blocks: XCD x gets swz in [64x, 64x+64) = batches 2x, 2x+1.
__device__ __forceinline__ int xcd_swz(int bid) {
    return (bid & 7) * 64 + (bid >> 3);
}

// ---------------------------------------------------------------------------
// K1: exact R16 (best measured). 512 blocks, 512 threads, 8 rows/block.
// Split-K quarters; phase 2 fused (ai+aj+g from one hs stream).
// ---------------------------------------------------------------------------
__global__ __launch_bounds__(512, 4) void gat_k1(
    const float* __restrict__ x, const float* __restrict__ W_fc,
    const float* __restrict__ b_fc, const float* __restrict__ W_a1,
    const float* __restrict__ b_a1, const float* __restrict__ W_out,
    float* __restrict__ aiT, float* __restrict__ ajT, float* __restrict__ g)
{
    __shared__ __align__(16) float xs[8][HID];            // 4KB
    __shared__ __align__(16) float hs[8][HID];            // 4KB
    __shared__ __align__(16) float red[4][3][8][HID];     // 48KB

    const int tid = threadIdx.x;
    const int k   = tid & 127;
    const int q   = tid >> 7;                 // 0..3
    const int swz = xcd_swz(blockIdx.x);
    const int r0  = swz * 8;                  // flat row = b*NN + n0
    const int b   = r0 >> 8;
    const int n0  = r0 & 255;

    for (int t = tid; t < 8 * HID; t += 512)
        xs[t >> 7][t & 127] = x[r0 * HID + t];
    __syncthreads();

    // ---- phase 1: h partials, split-K quarter d in [32q, 32q+32) ----
    {
        float acc[8] = {0,0,0,0,0,0,0,0};
        const int dq = 32 * q;
        #pragma unroll 2
        for (int d = 0; d < 32; d += 4) {
            float w[4];
            #pragma unroll
            for (int t = 0; t < 4; ++t) w[t] = W_fc[(dq + d + t) * HID + k];
            #pragma unroll
            for (int r = 0; r < 8; ++r) {
                const float4 xv = *(const float4*)&xs[r][dq + d];
                acc[r] += xv.x * w[0] + xv.y * w[1] + xv.z * w[2] + xv.w * w[3];
            }
        }
        #pragma unroll
        for (int r = 0; r < 8; ++r) red[q][0][r][k] = acc[r];
    }
    __syncthreads();

    // ---- reduce h: thread (k,q) -> rows 2q, 2q+1 ----
    {
        const float bf = b_fc[k];
        #pragma unroll
        for (int r2 = 0; r2 < 2; ++r2) {
            const int r = 2 * q + r2;
            hs[r][k] = (red[0][0][r][k] + red[1][0][r][k])
                     + (red[2][0][r][k] + red[3][0][r][k]) + bf;
        }
    }
    __syncthreads();

    // ---- phase 2 FUSED: ai+aj+g partials over d-quarter, one hs stream ----
    {
        float ai_a[8] = {0,0,0,0,0,0,0,0};
        float aj_a[8] = {0,0,0,0,0,0,0,0};
        float g_a[8]  = {0,0,0,0,0,0,0,0};
        const int dq = 32 * q;
        #pragma unroll 2
        for (int d = 0; d < 32; d += 4) {
            float wi[4], wj[4], wo[4];
            #pragma unroll
            for (int t = 0; t < 4; ++t) {
                wi[t] = W_a1[(dq + d + t) * HID + k];
                wj[t] = W_a1[(HID + dq + d + t) * HID + k];
                wo[t] = W_out[(dq + d + t) * HID + k];
            }
            #pragma unroll
            for (int r = 0; r < 8; ++r) {
                const float4 hv = *(const float4*)&hs[r][dq + d];
                ai_a[r] += hv.x * wi[0] + hv.y * wi[1] + hv.z * wi[2] + hv.w * wi[3];
                aj_a[r] += hv.x * wj[0] + hv.y * wj[1] + hv.z * wj[2] + hv.w * wj[3];
                g_a[r]  += hv.x * wo[0] + hv.y * wo[1] + hv.z * wo[2] + hv.w * wo[3];
            }
        }
        #pragma unroll
        for (int r = 0; r < 8; ++r) {
            red[q][0][r][k] = ai_a[r];
            red[q][1][r][k] = aj_a[r];
            red[q][2][r][k] = g_a[r];
        }
    }
    __syncthreads();

    // ---- reduce + stores ----
    {
        const int is_aj = q >> 1;
        const int rb4   = (q & 1) * 4;
        const float bias = is_aj ? 0.f : b_a1[k];
        float4 v;
        v.x = (red[0][is_aj][rb4 + 0][k] + red[1][is_aj][rb4 + 0][k])
            + (red[2][is_aj][rb4 + 0][k] + red[3][is_aj][rb4 + 0][k]) + bias;
        v.y = (red[0][is_aj][rb4 + 1][k] + red[1][is_aj][rb4 + 1][k])
            + (red[2][is_aj][rb4 + 1][k] + red[3][is_aj][rb4 + 1][k]) + bias;
        v.z = (red[0][is_aj][rb4 + 2][k] + red[1][is_aj][rb4 + 2][k])
            + (red[2][is_aj][rb4 + 2][k] + red[3][is_aj][rb4 + 2][k]) + bias;
        v.w = (red[0][is_aj][rb4 + 3][k] + red[1][is_aj][rb4 + 3][k])
            + (red[2][is_aj][rb4 + 3][k] + red[3][is_aj][rb4 + 3][k]) + bias;
        float* dst = (is_aj ? ajT : aiT) + (b * HID + k) * NN + n0 + rb4;
        *(float4*)dst = v;

        #pragma unroll
        for (int r2 = 0; r2 < 2; ++r2) {
            const int r = 2 * q + r2;
            g[(r0 + r) * HID + k] = (red[0][2][r][k] + red[1][2][r][k])
                                  + (red[2][2][r][k] + red[3][2][r][k]);
        }
    }
}

// ---------------------------------------------------------------------------
// K2: LOW-REDUNDANCY. 512 blocks, 512 threads, 8-row i-tile.
// Phase A: wave = (k-quarter kh, row-half rh), 4 rows x 256 j x 32 k ->
//   each ajT element read by 2 waves (256KB/block, was 512).
// Phase B: wave = j-octant, lane = k-pair, all 8 rows -> g read ONCE
//   (128KB/block, was 256). Partials via 32KB LDS (aliased).
// ---------------------------------------------------------------------------
__global__ __launch_bounds__(512, 4) void gat_k2(
    const float* __restrict__ aiT, const float* __restrict__ ajT,
    const float* __restrict__ g,  const int* __restrict__ adj,
    const float* __restrict__ w_a2, const float* __restrict__ b_a2,
    const float* __restrict__ b_out, float* __restrict__ out)
{
    __shared__ __align__(16) float4 aiwp[HID][2];        // 4KB {ai rows 4rh..4rh+3}
    __shared__ __align__(16) float  w2s[HID];            // 0.5KB
    __shared__ __align__(16) float  buf4[4][8][NN];      // 32KB e-partials; later red
    __shared__ __align__(16) float  ep[8][NN];           // 8KB p

    const int tid = threadIdx.x;
    const int swz = xcd_swz(blockIdx.x);
    const int b   = swz >> 5;
    const int i0  = (swz & 31) * 8;
    const int wv  = tid >> 6, lane = tid & 63;

    // staging: aiwp[kk][rh] = ai rows i0+4rh .. i0+4rh+3 (contiguous float4)
    if (tid < 256) {
        const int kk = tid >> 1, rh = tid & 1;
        aiwp[kk][rh] = *(const float4*)&aiT[(b * HID + kk) * NN + i0 + 4 * rh];
    } else if (tid < 384) {
        w2s[tid - 256] = w_a2[tid - 256];
    }
    // adj prefetch in softmax layout (row wv, cols 4*lane..+3)
    const int4 am = *(const int4*)(adj + (b * NN + i0 + wv) * NN + 4 * lane);
    __syncthreads();

    // ---- phase A: wave (kh = wv>>1, rh = wv&1): rows 4rh..4rh+3,
    //      kk in [32kh, 32kh+32), lane owns j = 4l..4l+3 ----
    {
        const int kh = wv >> 1, rh = wv & 1;
        const float* ajp = ajT + (b * HID + kh * 32) * NN + 4 * lane;
        float4 acc0 = {0,0,0,0}, acc1 = {0,0,0,0};
        float4 acc2 = {0,0,0,0}, acc3 = {0,0,0,0};
        float4 saw  = {0,0,0,0};
        const int kb = kh * 32;
        #pragma unroll 8
        for (int t = 0; t < 32; ++t) {
            const float4 a4 = *(const float4*)(ajp + t * NN);
            const float4 aw = aiwp[kb + t][rh];
            const float wk  = w2s[kb + t];
            saw.x  = __builtin_fmaf(a4.x, wk, saw.x);
            saw.y  = __builtin_fmaf(a4.y, wk, saw.y);
            saw.z  = __builtin_fmaf(a4.z, wk, saw.z);
            saw.w  = __builtin_fmaf(a4.w, wk, saw.w);
            acc0.x = __builtin_fmaf(fmaxf(aw.x, -a4.x), wk, acc0.x);
            acc0.y = __builtin_fmaf(fmaxf(aw.x, -a4.y), wk, acc0.y);
            acc0.z = __builtin_fmaf(fmaxf(aw.x, -a4.z), wk, acc0.z);
            acc0.w = __builtin_fmaf(fmaxf(aw.x, -a4.w), wk, acc0.w);
            acc1.x = __builtin_fmaf(fmaxf(aw.y, -a4.x), wk, acc1.x);
            acc1.y = __builtin_fmaf(fmaxf(aw.y, -a4.y), wk, acc1.y);
            acc1.z = __builtin_fmaf(fmaxf(aw.y, -a4.z), wk, acc1.z);
            acc1.w = __builtin_fmaf(fmaxf(aw.y, -a4.w), wk, acc1.w);
            acc2.x = __builtin_fmaf(fmaxf(aw.z, -a4.x), wk, acc2.x);
            acc2.y = __builtin_fmaf(fmaxf(aw.z, -a4.y), wk, acc2.y);
            acc2.z = __builtin_fmaf(fmaxf(aw.z, -a4.z), wk, acc2.z);
            acc2.w = __builtin_fmaf(fmaxf(aw.z, -a4.w), wk, acc2.w);
            acc3.x = __builtin_fmaf(fmaxf(aw.w, -a4.x), wk, acc3.x);
            acc3.y = __builtin_fmaf(fmaxf(aw.w, -a4.y), wk, acc3.y);
            acc3.z = __builtin_fmaf(fmaxf(aw.w, -a4.z), wk, acc3.z);
            acc3.w = __builtin_fmaf(fmaxf(aw.w, -a4.w), wk, acc3.w);
        }
        const int rb = 4 * rh;
        float4 e;
        e.x = acc0.x + saw.x; e.y = acc0.y + saw.y;
        e.z = acc0.z + saw.z; e.w = acc0.w + saw.w;
        *(float4*)&buf4[kh][rb + 0][4 * lane] = e;
        e.x = acc1.x + saw.x; e.y = acc1.y + saw.y;
        e.z = acc1.z + saw.z; e.w = acc1.w + saw.w;
        *(float4*)&buf4[kh][rb + 1][4 * lane] = e;
        e.x = acc2.x + saw.x; e.y = acc2.y + saw.y;
        e.z = acc2.z + saw.z; e.w = acc2.w + saw.w;
        *(float4*)&buf4[kh][rb + 2][4 * lane] = e;
        e.x = acc3.x + saw.x; e.y = acc3.y + saw.y;
        e.z = acc3.z + saw.z; e.w = acc3.w + saw.w;
        *(float4*)&buf4[kh][rb + 3][4 * lane] = e;
    }
    __syncthreads();

    // ---- mask + softmax: wave wv owns row wv (sum 4 k-quarter partials) ----
    {
        const float ba2 = b_a2[0];
        const float4 s0 = *(const float4*)&buf4[0][wv][4 * lane];
        const float4 s1 = *(const float4*)&buf4[1][wv][4 * lane];
        const float4 s2 = *(const float4*)&buf4[2][wv][4 * lane];
        const float4 s3 = *(const float4*)&buf4[3][wv][4 * lane];
        const float e0 = am.x ? (s0.x + s1.x) + (s2.x + s3.x) + ba2 : -1e9f;
        const float e1 = am.y ? (s0.y + s1.y) + (s2.y + s3.y) + ba2 : -1e9f;
        const float e2 = am.z ? (s0.z + s1.z) + (s2.z + s3.z) + ba2 : -1e9f;
        const float e3 = am.w ? (s0.w + s1.w) + (s2.w + s3.w) + ba2 : -1e9f;
        float m = fmaxf(fmaxf(e0, e1), fmaxf(e2, e3));
        #pragma unroll
        for (int off = 32; off; off >>= 1) m = fmaxf(m, __shfl_xor(m, off));
        const float p0 = __expf(e0 - m), p1 = __expf(e1 - m);
        const float p2 = __expf(e2 - m), p3 = __expf(e3 - m);
        float s = (p0 + p1) + (p2 + p3);
        #pragma unroll
        for (int off = 32; off; off >>= 1) s += __shfl_xor(s, off);
        const float inv = 1.f / s;
        const float4 pv = {p0 * inv, p1 * inv, p2 * inv, p3 * inv};
        *(float4*)&ep[wv][4 * lane] = pv;
    }
    __syncthreads();

    // ---- phase B: out-partials = P @ g. Wave = j-octant [32wv, 32wv+32);
    //      lane owns k-pair; all 8 rows -> g read exactly once per block ----
    float* red = &buf4[0][0][0];              // [8][8][HID] = 32KB, aliases buf4
    {
        float2 o[8];
        #pragma unroll
        for (int r = 0; r < 8; ++r) { o[r].x = 0.f; o[r].y = 0.f; }
        const int jb = 32 * wv;
        const float* gb = g + (b * NN + jb) * HID + 2 * lane;
        #pragma unroll 2
        for (int jq = 0; jq < 32; jq += 4) {
            const float2 g0 = *(const float2*)(gb + (jq + 0) * HID);
            const float2 g1 = *(const float2*)(gb + (jq + 1) * HID);
            const float2 g2 = *(const float2*)(gb + (jq + 2) * HID);
            const float2 g3 = *(const float2*)(gb + (jq + 3) * HID);
            #pragma unroll
            for (int r = 0; r < 8; ++r) {
                const float4 pv = *(const float4*)&ep[r][jb + jq];
                o[r].x += pv.x * g0.x + pv.y * g1.x + pv.z * g2.x + pv.w * g3.x;
                o[r].y += pv.x * g0.y + pv.y * g1.y + pv.z * g2.y + pv.w * g3.y;
            }
        }
        #pragma unroll
        for (int r = 0; r < 8; ++r)
            *(float2*)&red[(wv * 8 + r) * HID + 2 * lane] = o[r];
    }
    __syncthreads();

    // ---- final reduce: thread (k, q) -> rows 2q, 2q+1 (sum 8 octants) ----
    {
        const int k = tid & 127, q = tid >> 7;
        const float bo = b_out[k];
        #pragma unroll
        for (int r2 = 0; r2 < 2; ++r2) {
            const int r = 2 * q + r2;
            float s = 0.f;
            #pragma unroll
            for (int oct = 0; oct < 8; ++oct)
                s += red[(oct * 8 + r) * HID + k];
            out[(b * NN + i0 + r) * HID + k] = s + bo;
        }
    }
}

extern "C" void kernel_launch(void* const* d_in, const int* in_sizes, int n_in,
                              void* d_out, int out_size, void* d_ws, size_t ws_size,
                              hipStream_t stream) {
    const float* x     = (const float*)d_in[0];
    const int*   adj   = (const int*)  d_in[1];
    const float* W_fc  = (const float*)d_in[2];
    const float* b_fc  = (const float*)d_in[3];
    const float* W_a1  = (const float*)d_in[4];
    const float* b_a1  = (const float*)d_in[5];
    const float* w_a2  = (const float*)d_in[6];
    const float* b_a2  = (const float*)d_in[7];
    const float* W_out = (const float*)d_in[8];
    const float* b_out = (const float*)d_in[9];
    float* out = (float*)d_out;

    float* ws  = (float*)d_ws;
    float* aiT = ws;                      // aiT[b][k][n]
    float* ajT = ws + BS * NN * HID;      // ajT[b][k][n]
    float* g   = ws + 2 * BS * NN * HID;  // g = h@W_out, [b][n][k]

    gat_k1<<<BS * NN / 8, 512, 0, stream>>>(x, W_fc, b_fc, W_a1, b_a1, W_out,
                                            aiT, ajT, g);
    gat_k2<<<BS * (NN / 8), 512, 0, stream>>>(aiT, ajT, g, adj, w_a2, b_a2,
                                              b_out, out);
}